// Round 7
// baseline (730.456 us; speedup 1.0000x reference)
//
#include <hip/hip_runtime.h>
#include <hip/hip_bf16.h>
#include <stdint.h>

typedef __bf16 bf16;
typedef __attribute__((ext_vector_type(4))) __bf16 bf16x4;
typedef __attribute__((ext_vector_type(8))) __bf16 bf16x8;
typedef __attribute__((ext_vector_type(4))) float f32x4;
typedef __attribute__((ext_vector_type(4))) unsigned int u32x4;

#define NH 16
#define SEQ 2048
#define DH 64
#define NT 32
#define SCALE 0.125f
#define NEGINF (-1e30f)
#define IMG_TILE 8192

// DIAGNOSTIC ROUND: repeat counts chosen so each kernel's dispatch duration
// exceeds the ~156us harness poison-fills and surfaces in rocprof top-5 with
// full counters. Per-rep work identical to R6 -> divide durations by REP.
#define REP_PREP 16
#define REP_ATTN 5

// ws layout: [0,64) flag; [64, 64+512*64) tile lists; then K/V fragment images.
struct TileList { int count; int pad[3]; unsigned char e[32]; int pad2[4]; }; // 64 B
#define WS_LISTS 64
#define WS_KIMG  65536
#define WS_VIMG  (WS_KIMG + (size_t)NH * NT * IMG_TILE)
#define WS_NEED  (WS_VIMG + (size_t)NH * NT * IMG_TILE)

// XOR swizzle for the wave-private 16x64 bf16 P tile ([16][128B] rows).
__device__ __forceinline__ unsigned swz16(int row, int bytecol) {
  return (unsigned)(row * 128 + (bytecol ^ ((row & 7) << 4)));
}

// ---------------------------------------------------------------------------
// prep: (a) classify mask dtype; (b) per-(h,qtile) active-ktile lists;
// (c) [CONV] K and V^T in MFMA fragment-image layout. Body repeated REP_PREP
// times (idempotent global stores -> not DCE-able, identical per rep).
// ---------------------------------------------------------------------------
template<bool CONV>
__global__ void __launch_bounds__(256) prep_kernel(
    const float* __restrict__ kg, const float* __restrict__ vg,
    const void* __restrict__ maskg, unsigned char* __restrict__ ws)
{
  const int b = blockIdx.x, tid = threadIdx.x;
  const int l = tid & 63, w = tid >> 6;
  const int h = b & 15, x = b >> 4;

  __shared__ int cls;
  __shared__ unsigned sOr[4][32], sAnd[4][32];
  __shared__ unsigned char tfl[32];

  if (tid == 0) cls = 0;
  __syncthreads();
  {  // dtype classify: byte-bool -> 0x01010101 dwords; int32-bool -> 1 dwords
    u32x4 t = ((const u32x4*)maskg)[tid];
    int bits = 0;
    #pragma unroll
    for (int j = 0; j < 4; ++j) {
      if (t[j] == 0x01010101u) bits |= 1;
      else if (t[j] == 1u) bits |= 2;
    }
    const int wb = (__any(bits & 1) ? 1 : 0) | (__any(bits & 2) ? 2 : 0);
    if (l == 0 && wb) atomicOr(&cls, wb);
  }
  __syncthreads();
  const int byteMode = ((cls & 1) || !(cls & 2)) ? 1 : 0;
  if (b == 0 && tid == 0) *(int*)ws = byteMode ? 1 : 2;

  for (int rep = 0; rep < REP_PREP; ++rep) {
    // ---- K/V fragment-image conversion (tile x as ktile) ----
    if constexpr (CONV) {
      const int kb = x << 6;
      unsigned char* kimg = ws + WS_KIMG + (size_t)(h * NT + x) * IMG_TILE;
      unsigned char* vimg = ws + WS_VIMG + (size_t)(h * NT + x) * IMG_TILE;
      #pragma unroll
      for (int i = 0; i < 2; ++i) {
        const int g = 2 * w + i, nd = g >> 1, ks = g & 1;
        const float* kr = kg + ((size_t)(h * SEQ) + kb + 16 * nd + (l & 15)) * DH
                          + ks * 32 + (l >> 4) * 8;
        f32x4 a0 = ((const f32x4*)kr)[0], a1 = ((const f32x4*)kr)[1];
        bf16x8 kb8;
        #pragma unroll
        for (int j = 0; j < 4; ++j) { kb8[j] = (bf16)a0[j]; kb8[4 + j] = (bf16)a1[j]; }
        *(bf16x8*)(kimg + (g * 64 + l) * 16) = kb8;

        const float* vb = vg + ((size_t)(h * SEQ) + kb + ks * 32 + (l >> 4) * 8) * DH
                          + 16 * nd + (l & 15);
        bf16x8 vb8;
        #pragma unroll
        for (int j = 0; j < 8; ++j) vb8[j] = (bf16)vb[j * DH];
        *(bf16x8*)(vimg + (g * 64 + l) * 16) = vb8;
      }
    }

    // ---- coalesced mask scan (tile x as qtile) ----
    const int qb = x << 6;
    if (byteMode) {
      const unsigned char* st = (const unsigned char*)maskg + ((size_t)(h * SEQ) + qb) * SEQ;
      unsigned o0 = 0, a0 = 0xFFFFFFFFu, o1 = 0, a1 = 0xFFFFFFFFu;
      for (int p = 0; p < 16; ++p) {
        const int row = p * 4 + w;
        u32x4 ta = *(const u32x4*)(st + (size_t)row * SEQ + l * 16);
        u32x4 tb = *(const u32x4*)(st + (size_t)row * SEQ + 1024 + l * 16);
        o0 |= ta[0] | ta[1] | ta[2] | ta[3]; a0 &= ta[0] & ta[1] & ta[2] & ta[3];
        o1 |= tb[0] | tb[1] | tb[2] | tb[3]; a1 &= tb[0] & tb[1] & tb[2] & tb[3];
      }
      #pragma unroll
      for (int d = 1; d <= 2; d <<= 1) {
        o0 |= __shfl_xor(o0, d); a0 &= __shfl_xor(a0, d);
        o1 |= __shfl_xor(o1, d); a1 &= __shfl_xor(a1, d);
      }
      if ((l & 3) == 0) {
        sOr[w][l >> 2] = o0;        sAnd[w][l >> 2] = a0;
        sOr[w][16 + (l >> 2)] = o1; sAnd[w][16 + (l >> 2)] = a1;
      }
    } else {
      const unsigned char* st = (const unsigned char*)maskg + ((size_t)(h * SEQ) + qb) * SEQ * 4;
      unsigned oc[8], ac[8];
      #pragma unroll
      for (int c = 0; c < 8; ++c) { oc[c] = 0; ac[c] = 0xFFFFFFFFu; }
      for (int p = 0; p < 16; ++p) {
        const int row = p * 4 + w;
        #pragma unroll
        for (int c = 0; c < 8; ++c) {
          u32x4 t = *(const u32x4*)(st + (size_t)row * SEQ * 4 + c * 1024 + l * 16);
          oc[c] |= t[0] | t[1] | t[2] | t[3];
          ac[c] &= t[0] & t[1] & t[2] & t[3];
        }
      }
      #pragma unroll
      for (int d = 1; d <= 8; d <<= 1) {
        #pragma unroll
        for (int c = 0; c < 8; ++c) {
          oc[c] |= __shfl_xor(oc[c], d); ac[c] &= __shfl_xor(ac[c], d);
        }
      }
      if ((l & 15) == 0) {
        #pragma unroll
        for (int c = 0; c < 8; ++c) {
          sOr[w][c * 4 + (l >> 4)] = oc[c];
          sAnd[w][c * 4 + (l >> 4)] = ac[c];
        }
      }
    }
    __syncthreads();
    if (tid < 32) {
      const unsigned o = sOr[0][tid] | sOr[1][tid] | sOr[2][tid] | sOr[3][tid];
      const unsigned a = sAnd[0][tid] & sAnd[1][tid] & sAnd[2][tid] & sAnd[3][tid];
      int all = 0;
      if (o == a && a != 0u) {
        if (byteMode)
          all = ((((a & 0x7F7F7F7Fu) + 0x7F7F7F7Fu) | a) & 0x80808080u) == 0x80808080u;
        else all = 1;
      }
      tfl[tid] = (unsigned char)((o != 0u ? 1 : 0) | (all ? 2 : 0));
    }
    __syncthreads();
    if (tid == 0) {
      TileList* L = (TileList*)(ws + WS_LISTS) + (h * NT + x);
      int n = 0;
      for (int kt = 0; kt < NT; ++kt) {
        const unsigned f = tfl[kt];
        if (f & 1) L->e[n++] = (unsigned char)(kt | ((f & 2) ? 0x80 : 0));
      }
      L->count = n;
    }
    __syncthreads();   // protect tfl/sOr before next rep overwrites
  }
}

// ---------------------------------------------------------------------------
// attn: identical per-rep to R6 (swapped-operand, barrier-free, register K/V
// frags from images, wave-private P LDS). Main loop repeated REP_ATTN times
// with full state reset; earlier reps kept alive via asm (anti-DCE, rule 17);
// epilogue uses the (identical) last rep.
// ---------------------------------------------------------------------------
template<bool IMG>
__global__ void __launch_bounds__(256, 2) attn_kernel(
    const float* __restrict__ qg, const float* __restrict__ kg,
    const float* __restrict__ vg, const void* __restrict__ maskg,
    float* __restrict__ outg, const unsigned char* __restrict__ ws)
{
  const int bid = blockIdx.x;
  const int h = bid & 15, qt = bid >> 4, qb = qt << 6;
  const int tid = threadIdx.x, l = tid & 63, rw = tid >> 6;
  const int qrow = l & 15, kgrp = l >> 4;
  const int byteMode = (*(const int*)ws == 2) ? 0 : 1;

  __shared__ __attribute__((aligned(16))) bf16 Pl[4][1024];
  __shared__ unsigned char Ll[32];

  const TileList* L = (const TileList*)(ws + WS_LISTS) + (h * NT + qt);
  const int cnt = L->count;
  if (tid < 32) Ll[tid] = L->e[tid];

  bf16x8 qa[2];
  {
    const float* qp = qg + ((size_t)(h * SEQ) + qb + 16 * rw + qrow) * DH;
    #pragma unroll
    for (int ks = 0; ks < 2; ++ks) {
      f32x4 x0 = *(const f32x4*)(qp + ks * 32 + kgrp * 8);
      f32x4 x1 = *(const f32x4*)(qp + ks * 32 + kgrp * 8 + 4);
      bf16x8 a;
      #pragma unroll
      for (int j = 0; j < 4; ++j) {
        a[j] = (bf16)(x0[j] * SCALE); a[4 + j] = (bf16)(x1[j] * SCALE);
      }
      qa[ks] = a;
    }
  }
  __syncthreads();   // Ll ready

  const unsigned char* kimg = ws + WS_KIMG + (size_t)h * NT * IMG_TILE;
  const unsigned char* vimg = ws + WS_VIMG + (size_t)h * NT * IMG_TILE;

  auto loadK = [&](bf16x8* kf, int kt) {
    if constexpr (IMG) {
      const unsigned char* kp = kimg + (size_t)kt * IMG_TILE + l * 16;
      #pragma unroll
      for (int g = 0; g < 8; ++g) kf[g] = *(const bf16x8*)(kp + g * 1024);
    } else {
      const int kb = kt << 6;
      #pragma unroll
      for (int g = 0; g < 8; ++g) {
        const int nd = g >> 1, ks = g & 1;
        const float* kr = kg + ((size_t)(h * SEQ) + kb + 16 * nd + qrow) * DH
                          + ks * 32 + kgrp * 8;
        f32x4 x0 = ((const f32x4*)kr)[0], x1 = ((const f32x4*)kr)[1];
        #pragma unroll
        for (int j = 0; j < 4; ++j) { kf[g][j] = (bf16)x0[j]; kf[g][4 + j] = (bf16)x1[j]; }
      }
    }
  };

  char* pw = (char*)Pl[rw];

  f32x4 oacc[4];
  float mrun, lrun;

  for (int rep = 0; rep < REP_ATTN; ++rep) {
    #pragma unroll
    for (int nd = 0; nd < 4; ++nd) oacc[nd] = (f32x4){0.f, 0.f, 0.f, 0.f};
    mrun = NEGINF; lrun = 0.f;

    bf16x8 kf[8];
    if (cnt > 0) loadK(kf, Ll[0] & 63);

    for (int i = 0; i < cnt; ++i) {
      const unsigned e = Ll[i];
      const int kt = e & 63;
      const int allT = (e & 0x80u) != 0;
      const int kb = kt << 6;

      // ---- S^T = K Q^T ----
      f32x4 sfr[4];
      #pragma unroll
      for (int nd = 0; nd < 4; ++nd) sfr[nd] = (f32x4){0.f, 0.f, 0.f, 0.f};
      __builtin_amdgcn_s_setprio(1);
      #pragma unroll
      for (int nd = 0; nd < 4; ++nd)
        #pragma unroll
        for (int ks = 0; ks < 2; ++ks)
          sfr[nd] = __builtin_amdgcn_mfma_f32_16x16x32_bf16(kf[nd * 2 + ks], qa[ks], sfr[nd], 0, 0, 0);
      __builtin_amdgcn_s_setprio(0);

      if (i + 1 < cnt) loadK(kf, Ll[i + 1] & 63);

      bf16x8 vf[8];
      if constexpr (IMG) {
        const unsigned char* vp = vimg + (size_t)kt * IMG_TILE + l * 16;
        #pragma unroll
        for (int g = 0; g < 8; ++g) vf[g] = *(const bf16x8*)(vp + g * 1024);
      } else {
        #pragma unroll
        for (int g = 0; g < 8; ++g) {
          const int nd = g >> 1, ks = g & 1;
          const float* vb = vg + ((size_t)(h * SEQ) + kb + ks * 32 + kgrp * 8) * DH
                            + 16 * nd + qrow;
          #pragma unroll
          for (int j = 0; j < 8; ++j) vf[g][j] = (bf16)vb[j * DH];
        }
      }

      if (!allT) {
        const size_t base = ((size_t)(h * SEQ) + qb + 16 * rw + qrow) * SEQ + kb + 4 * kgrp;
        #pragma unroll
        for (int nd = 0; nd < 4; ++nd)
          #pragma unroll
          for (int r = 0; r < 4; ++r) {
            const size_t off = base + 16 * nd + r;
            const bool mv = byteMode ? (((const unsigned char*)maskg)[off] != 0)
                                     : (((const unsigned*)maskg)[off] != 0u);
            if (!mv) sfr[nd][r] = NEGINF;
          }
      }

      // ---- per-lane online softmax (2 shuffles total) ----
      float mt;
      {
        f32x4 t0, t1;
        #pragma unroll
        for (int r = 0; r < 4; ++r) {
          t0[r] = fmaxf(sfr[0][r], sfr[1][r]);
          t1[r] = fmaxf(sfr[2][r], sfr[3][r]);
        }
        mt = fmaxf(fmaxf(fmaxf(t0[0], t0[1]), fmaxf(t0[2], t0[3])),
                   fmaxf(fmaxf(t1[0], t1[1]), fmaxf(t1[2], t1[3])));
      }
      mt = fmaxf(mt, __shfl_xor(mt, 16));
      mt = fmaxf(mt, __shfl_xor(mt, 32));
      const float mn = fmaxf(mrun, mt);
      const float fac = __expf(mrun - mn);
      float ls = 0.f;
      bf16x4 pb[4];
      #pragma unroll
      for (int nd = 0; nd < 4; ++nd)
        #pragma unroll
        for (int r = 0; r < 4; ++r) {
          const float p = (sfr[nd][r] > -1e20f) ? __expf(sfr[nd][r] - mn) : 0.f;
          ls += p; pb[nd][r] = (bf16)p;
        }
      ls += __shfl_xor(ls, 16);
      ls += __shfl_xor(ls, 32);
      lrun = lrun * fac + ls;
      mrun = mn;
      #pragma unroll
      for (int nd = 0; nd < 4; ++nd)
        #pragma unroll
        for (int r = 0; r < 4; ++r) oacc[nd][r] *= fac;

      // ---- P -> wave-private LDS, read back as B-frags ----
      #pragma unroll
      for (int nd = 0; nd < 4; ++nd)
        *(bf16x4*)(pw + swz16(qrow, 32 * nd + 8 * kgrp)) = pb[nd];
      bf16x8 ap[2];
      #pragma unroll
      for (int ks = 0; ks < 2; ++ks)
        ap[ks] = *(const bf16x8*)(pw + swz16(qrow, 64 * ks + 16 * kgrp));

      // ---- O^T += V^T P ----
      __builtin_amdgcn_s_setprio(1);
      #pragma unroll
      for (int ks = 0; ks < 2; ++ks)
        #pragma unroll
        for (int nd = 0; nd < 4; ++nd)
          oacc[nd] = __builtin_amdgcn_mfma_f32_16x16x32_bf16(vf[nd * 2 + ks], ap[ks], oacc[nd], 0, 0, 0);
      __builtin_amdgcn_s_setprio(0);
    }

    // anti-DCE: keep every rep's results live (rule #17)
    asm volatile("" ::
      "v"(mrun), "v"(lrun),
      "v"(oacc[0][0]), "v"(oacc[0][1]), "v"(oacc[0][2]), "v"(oacc[0][3]),
      "v"(oacc[1][0]), "v"(oacc[1][1]), "v"(oacc[1][2]), "v"(oacc[1][3]),
      "v"(oacc[2][0]), "v"(oacc[2][1]), "v"(oacc[2][2]), "v"(oacc[2][3]),
      "v"(oacc[3][0]), "v"(oacc[3][1]), "v"(oacc[3][2]), "v"(oacc[3][3]));
  }

  // ---- epilogue (lane-local, coalesced 16B stores) ----
  {
    const float inv = (lrun > 0.f) ? (1.f / lrun) : 0.f;
    const int grow = qb + 16 * rw + qrow;
    float* op = outg + ((size_t)(h * SEQ) + grow) * DH + 4 * kgrp;
    #pragma unroll
    for (int nd = 0; nd < 4; ++nd) {
      f32x4 o;
      #pragma unroll
      for (int r = 0; r < 4; ++r) o[r] = oacc[nd][r] * inv;
      *(f32x4*)(op + 16 * nd) = o;
    }
  }
}

extern "C" void kernel_launch(void* const* d_in, const int* in_sizes, int n_in,
                              void* d_out, int out_size, void* d_ws, size_t ws_size,
                              hipStream_t stream) {
  const float* q = (const float*)d_in[0];
  const float* k = (const float*)d_in[1];
  const float* v = (const float*)d_in[2];
  const void*  m = d_in[3];
  float* out = (float*)d_out;
  unsigned char* ws = (unsigned char*)d_ws;

  if (ws_size >= WS_NEED) {
    prep_kernel<true><<<NH * NT, 256, 0, stream>>>(k, v, m, ws);
    attn_kernel<true><<<NH * NT, 256, 0, stream>>>(q, k, v, m, out, ws);
  } else {
    prep_kernel<false><<<NH * NT, 256, 0, stream>>>(k, v, m, ws);
    attn_kernel<false><<<NH * NT, 256, 0, stream>>>(q, k, v, m, out, ws);
  }
}

// Round 8
// 81.077 us; speedup vs baseline: 9.0094x; 9.0094x over previous
//
#include <hip/hip_runtime.h>
#include <hip/hip_bf16.h>
#include <stdint.h>

typedef __bf16 bf16;
typedef __attribute__((ext_vector_type(4))) __bf16 bf16x4;
typedef __attribute__((ext_vector_type(8))) __bf16 bf16x8;
typedef __attribute__((ext_vector_type(4))) float f32x4;
typedef __attribute__((ext_vector_type(4))) unsigned int u32x4;

#define NH 16
#define SEQ 2048
#define DH 64
#define NT 32
#define SCALE 0.125f
#define NEGINF (-1e30f)
#define IMG_TILE 8192

// ws layout: [0,64) dtype flag; [64, 64+16KB) per-(h,qt) ktile flag bytes;
// then K/V fragment images.
#define WS_FLAGS 64
#define WS_KIMG  65536
#define WS_VIMG  (WS_KIMG + (size_t)NH * NT * IMG_TILE)
#define WS_NEED  (WS_VIMG + (size_t)NH * NT * IMG_TILE)

// XOR swizzle for the wave-private 16x64 bf16 P tile ([16][128B] rows).
__device__ __forceinline__ unsigned swz16(int row, int bytecol) {
  return (unsigned)(row * 128 + (bytecol ^ ((row & 7) << 4)));
}

// ---------------------------------------------------------------------------
// prep, restructured for occupancy (R7 diag: 42us @ 3.3TB/s, 21.5% occ —
// parallelism-starved streaming). Grid = [512 conv blocks] + 2048 scan blocks.
//  conv block b<512: (h=b&15, kt=b>>4): stage 64x64 f32 K (then V) tile
//    through padded LDS with coalesced row reads; emit bf16 fragment images:
//      K  slot(g,l): K[kb+16nd+(l&15)][ks*32+(l>>4)*8 + 0..7]   (g=nd*2+ks)
//      V  slot(g,l): V[kb+ks*32+(l>>4)*8 + 0..7][16nd+(l&15)]
//  scan block: (h, qt, kq): 64 rows x 512B of mask, per-ktile any/all via
//    in-wave shfl reduce + LDS combine; writes 8 flag bytes. No atomics.
// ---------------------------------------------------------------------------
template<bool CONV>
__global__ void __launch_bounds__(256) prep_kernel(
    const float* __restrict__ kg, const float* __restrict__ vg,
    const void* __restrict__ maskg, unsigned char* __restrict__ ws)
{
  const int b = blockIdx.x, tid = threadIdx.x;
  const int l = tid & 63, w = tid >> 6;

  __shared__ int cls;
  __shared__ unsigned sOr[4][8], sAnd[4][8];
  __shared__ float T[64][65];   // conv staging (padded: +65 -> bank spread)

  if constexpr (CONV) {
    if (b < 512) {
      // ---------------- conversion block ----------------
      const int h = b & 15, kt = b >> 4, kb = kt << 6;
      unsigned char* kimg = ws + WS_KIMG + (size_t)(h * NT + kt) * IMG_TILE;
      unsigned char* vimg = ws + WS_VIMG + (size_t)(h * NT + kt) * IMG_TILE;
      const int row = tid >> 2, c0 = (tid & 3) * 16;

      {   // stage K rows (coalesced 64B/thread)
        const f32x4* rp = (const f32x4*)(kg + ((size_t)(h * SEQ) + kb + row) * DH + c0);
        f32x4 a0 = rp[0], a1 = rp[1], a2 = rp[2], a3 = rp[3];
        float* d = &T[row][c0];
        #pragma unroll
        for (int j = 0; j < 4; ++j) {
          d[j] = a0[j]; d[4 + j] = a1[j]; d[8 + j] = a2[j]; d[12 + j] = a3[j];
        }
      }
      __syncthreads();
      #pragma unroll
      for (int i = 0; i < 2; ++i) {   // emit K image
        const int slot = tid + 256 * i, g = slot >> 6, ll = slot & 63;
        const int nd = g >> 1, ks = g & 1;
        const float* s = &T[16 * nd + (ll & 15)][ks * 32 + (ll >> 4) * 8];
        bf16x8 o;
        #pragma unroll
        for (int j = 0; j < 8; ++j) o[j] = (bf16)s[j];
        *(bf16x8*)(kimg + slot * 16) = o;
      }
      __syncthreads();
      {   // stage V rows
        const f32x4* rp = (const f32x4*)(vg + ((size_t)(h * SEQ) + kb + row) * DH + c0);
        f32x4 a0 = rp[0], a1 = rp[1], a2 = rp[2], a3 = rp[3];
        float* d = &T[row][c0];
        #pragma unroll
        for (int j = 0; j < 4; ++j) {
          d[j] = a0[j]; d[4 + j] = a1[j]; d[8 + j] = a2[j]; d[12 + j] = a3[j];
        }
      }
      __syncthreads();
      #pragma unroll
      for (int i = 0; i < 2; ++i) {   // emit V^T image (column gather from LDS)
        const int slot = tid + 256 * i, g = slot >> 6, ll = slot & 63;
        const int nd = g >> 1, ks = g & 1;
        const int r0 = ks * 32 + (ll >> 4) * 8, col = 16 * nd + (ll & 15);
        bf16x8 o;
        #pragma unroll
        for (int j = 0; j < 8; ++j) o[j] = (bf16)T[r0 + j][col];
        *(bf16x8*)(vimg + slot * 16) = o;
      }
      return;
    }
  }

  // ---------------- scan block ----------------
  const int sb = CONV ? (b - 512) : b;
  const int h = sb & 15, qt = (sb >> 4) & 31, kq = sb >> 9;
  const int qb = qt << 6;

  if (tid == 0) cls = 0;
  __syncthreads();
  {  // dtype classify from mask[0..4KB): byte-bool -> 0x01010101, int32 -> 1
    u32x4 t = ((const u32x4*)maskg)[tid];
    int bits = 0;
    #pragma unroll
    for (int j = 0; j < 4; ++j) {
      if (t[j] == 0x01010101u) bits |= 1;
      else if (t[j] == 1u) bits |= 2;
    }
    const int wb = (__any(bits & 1) ? 1 : 0) | (__any(bits & 2) ? 2 : 0);
    if (l == 0 && wb) atomicOr(&cls, wb);
  }
  __syncthreads();
  const int byteMode = ((cls & 1) || !(cls & 2)) ? 1 : 0;
  if (sb == 0 && tid == 0) *(int*)ws = byteMode ? 1 : 2;

  if (byteMode) {
    const unsigned char* st = (const unsigned char*)maskg
                              + ((size_t)(h * SEQ) + qb) * SEQ + kq * 512;
    unsigned o = 0u, a = 0xFFFFFFFFu;
    #pragma unroll
    for (int it = 0; it < 8; ++it) {
      const int row = w * 16 + 2 * it + (l >> 5);
      u32x4 t = *(const u32x4*)(st + (size_t)row * SEQ + (l & 31) * 16);
      o |= t[0] | t[1] | t[2] | t[3];
      a &= t[0] & t[1] & t[2] & t[3];
    }
    o |= __shfl_xor(o, 1);  a &= __shfl_xor(a, 1);
    o |= __shfl_xor(o, 2);  a &= __shfl_xor(a, 2);
    o |= __shfl_xor(o, 32); a &= __shfl_xor(a, 32);
    if ((l & 3) == 0 && l < 32) { sOr[w][l >> 2] = o; sAnd[w][l >> 2] = a; }
  } else {
    const unsigned char* st = (const unsigned char*)maskg
                              + (((size_t)(h * SEQ) + qb) * SEQ + kq * 512) * 4;
    unsigned oA = 0u, aA = 0xFFFFFFFFu, oB = 0u, aB = 0xFFFFFFFFu;
    #pragma unroll
    for (int it = 0; it < 16; ++it) {
      const unsigned char* rp = st + (size_t)(w * 16 + it) * (SEQ * 4);
      u32x4 ta = *(const u32x4*)(rp + l * 16);
      u32x4 tb = *(const u32x4*)(rp + 1024 + l * 16);
      oA |= ta[0] | ta[1] | ta[2] | ta[3]; aA &= ta[0] & ta[1] & ta[2] & ta[3];
      oB |= tb[0] | tb[1] | tb[2] | tb[3]; aB &= tb[0] & tb[1] & tb[2] & tb[3];
    }
    #pragma unroll
    for (int d = 1; d <= 8; d <<= 1) {
      oA |= __shfl_xor(oA, d); aA &= __shfl_xor(aA, d);
      oB |= __shfl_xor(oB, d); aB &= __shfl_xor(aB, d);
    }
    if ((l & 15) == 0) {
      sOr[w][l >> 4] = oA;     sAnd[w][l >> 4] = aA;
      sOr[w][4 + (l >> 4)] = oB; sAnd[w][4 + (l >> 4)] = aB;
    }
  }
  __syncthreads();
  if (tid < 8) {
    const unsigned o = sOr[0][tid] | sOr[1][tid] | sOr[2][tid] | sOr[3][tid];
    const unsigned a = sAnd[0][tid] & sAnd[1][tid] & sAnd[2][tid] & sAnd[3][tid];
    int all = 0;
    if (o == a && a != 0u) {   // all granules identical & nonzero
      if (byteMode)            // additionally require every byte nonzero
        all = ((((a & 0x7F7F7F7Fu) + 0x7F7F7F7Fu) | a) & 0x80808080u) == 0x80808080u;
      else all = 1;
    }
    ws[WS_FLAGS + (size_t)(h * NT + qt) * 32 + kq * 8 + tid] =
        (unsigned char)((o != 0u ? 1 : 0) | (all ? 2 : 0));
  }
}

// ---------------------------------------------------------------------------
// attn (unchanged from R6 except list source): block = (h=bid&15, qt=bid>>4),
// 4 waves; wave rw owns q-rows [qb+16rw,+16) and walks the whole active list.
// Swapped-operand: S^T = mfma(K,Q); lane qrow = l&15 owns one q-row; softmax
// in-reg + 2 shuffles; O^T = mfma(V^T,P); P via wave-private LDS; K frags
// prefetched 1 tile ahead. (256,2) -> no spills.
// ---------------------------------------------------------------------------
template<bool IMG>
__global__ void __launch_bounds__(256, 2) attn_kernel(
    const float* __restrict__ qg, const float* __restrict__ kg,
    const float* __restrict__ vg, const void* __restrict__ maskg,
    float* __restrict__ outg, const unsigned char* __restrict__ ws)
{
  const int bid = blockIdx.x;
  const int h = bid & 15, qt = bid >> 4, qb = qt << 6;
  const int tid = threadIdx.x, l = tid & 63, rw = tid >> 6;
  const int qrow = l & 15, kgrp = l >> 4;
  const int byteMode = (*(const int*)ws == 2) ? 0 : 1;

  __shared__ __attribute__((aligned(16))) bf16 Pl[4][1024];
  __shared__ unsigned char Ll[32];
  __shared__ int lcnt;

  // build active list from precomputed flag bytes
  if (tid == 0) {
    const unsigned char* fp = ws + WS_FLAGS + (size_t)(h * NT + qt) * 32;
    int n = 0;
    for (int kt2 = 0; kt2 < NT; ++kt2) {
      const unsigned f = fp[kt2];
      if (f & 1) Ll[n++] = (unsigned char)(kt2 | ((f & 2) ? 0x80 : 0));
    }
    lcnt = n;
  }

  bf16x8 qa[2];
  {
    const float* qp = qg + ((size_t)(h * SEQ) + qb + 16 * rw + qrow) * DH;
    #pragma unroll
    for (int ks = 0; ks < 2; ++ks) {
      f32x4 x0 = *(const f32x4*)(qp + ks * 32 + kgrp * 8);
      f32x4 x1 = *(const f32x4*)(qp + ks * 32 + kgrp * 8 + 4);
      bf16x8 a;
      #pragma unroll
      for (int j = 0; j < 4; ++j) {
        a[j] = (bf16)(x0[j] * SCALE); a[4 + j] = (bf16)(x1[j] * SCALE);
      }
      qa[ks] = a;
    }
  }
  __syncthreads();   // Ll/lcnt ready
  const int cnt = lcnt;

  f32x4 oacc[4];     // O^T frags: lane holds O[qrow][d = 16nd + 4kgrp + r]
  #pragma unroll
  for (int nd = 0; nd < 4; ++nd) oacc[nd] = (f32x4){0.f, 0.f, 0.f, 0.f};
  float mrun = NEGINF, lrun = 0.f;

  const unsigned char* kimg = ws + WS_KIMG + (size_t)h * NT * IMG_TILE;
  const unsigned char* vimg = ws + WS_VIMG + (size_t)h * NT * IMG_TILE;

  auto loadK = [&](bf16x8* kf, int kt) {
    if constexpr (IMG) {
      const unsigned char* kp = kimg + (size_t)kt * IMG_TILE + l * 16;
      #pragma unroll
      for (int g = 0; g < 8; ++g) kf[g] = *(const bf16x8*)(kp + g * 1024);
    } else {
      const int kb = kt << 6;
      #pragma unroll
      for (int g = 0; g < 8; ++g) {
        const int nd = g >> 1, ks = g & 1;
        const float* kr = kg + ((size_t)(h * SEQ) + kb + 16 * nd + qrow) * DH
                          + ks * 32 + kgrp * 8;
        f32x4 x0 = ((const f32x4*)kr)[0], x1 = ((const f32x4*)kr)[1];
        #pragma unroll
        for (int j = 0; j < 4; ++j) { kf[g][j] = (bf16)x0[j]; kf[g][4 + j] = (bf16)x1[j]; }
      }
    }
  };

  bf16x8 kf[8];
  if (cnt > 0) loadK(kf, Ll[0] & 63);

  char* pw = (char*)Pl[rw];

  for (int i = 0; i < cnt; ++i) {
    const unsigned e = Ll[i];
    const int kt = e & 63;
    const int allT = (e & 0x80u) != 0;
    const int kb = kt << 6;

    // ---- S^T = K Q^T : lane holds S[key = 16nd+4kgrp+r][qrow] ----
    f32x4 sfr[4];
    #pragma unroll
    for (int nd = 0; nd < 4; ++nd) sfr[nd] = (f32x4){0.f, 0.f, 0.f, 0.f};
    __builtin_amdgcn_s_setprio(1);
    #pragma unroll
    for (int nd = 0; nd < 4; ++nd)
      #pragma unroll
      for (int ks = 0; ks < 2; ++ks)
        sfr[nd] = __builtin_amdgcn_mfma_f32_16x16x32_bf16(kf[nd * 2 + ks], qa[ks], sfr[nd], 0, 0, 0);
    __builtin_amdgcn_s_setprio(0);

    if (i + 1 < cnt) loadK(kf, Ll[i + 1] & 63);

    bf16x8 vf[8];
    if constexpr (IMG) {
      const unsigned char* vp = vimg + (size_t)kt * IMG_TILE + l * 16;
      #pragma unroll
      for (int g = 0; g < 8; ++g) vf[g] = *(const bf16x8*)(vp + g * 1024);
    } else {
      #pragma unroll
      for (int g = 0; g < 8; ++g) {
        const int nd = g >> 1, ks = g & 1;
        const float* vb = vg + ((size_t)(h * SEQ) + kb + ks * 32 + kgrp * 8) * DH
                          + 16 * nd + qrow;
        #pragma unroll
        for (int j = 0; j < 8; ++j) vf[g][j] = (bf16)vb[j * DH];
      }
    }

    if (!allT) {
      const size_t base = ((size_t)(h * SEQ) + qb + 16 * rw + qrow) * SEQ + kb + 4 * kgrp;
      #pragma unroll
      for (int nd = 0; nd < 4; ++nd)
        #pragma unroll
        for (int r = 0; r < 4; ++r) {
          const size_t off = base + 16 * nd + r;
          const bool mv = byteMode ? (((const unsigned char*)maskg)[off] != 0)
                                   : (((const unsigned*)maskg)[off] != 0u);
          if (!mv) sfr[nd][r] = NEGINF;
        }
    }

    // ---- per-lane online softmax (2 shuffles total) ----
    float mt;
    {
      f32x4 t0, t1;
      #pragma unroll
      for (int r = 0; r < 4; ++r) {
        t0[r] = fmaxf(sfr[0][r], sfr[1][r]);
        t1[r] = fmaxf(sfr[2][r], sfr[3][r]);
      }
      mt = fmaxf(fmaxf(fmaxf(t0[0], t0[1]), fmaxf(t0[2], t0[3])),
                 fmaxf(fmaxf(t1[0], t1[1]), fmaxf(t1[2], t1[3])));
    }
    mt = fmaxf(mt, __shfl_xor(mt, 16));
    mt = fmaxf(mt, __shfl_xor(mt, 32));
    const float mn = fmaxf(mrun, mt);
    const float fac = __expf(mrun - mn);
    float ls = 0.f;
    bf16x4 pb[4];
    #pragma unroll
    for (int nd = 0; nd < 4; ++nd)
      #pragma unroll
      for (int r = 0; r < 4; ++r) {
        const float p = (sfr[nd][r] > -1e20f) ? __expf(sfr[nd][r] - mn) : 0.f;
        ls += p; pb[nd][r] = (bf16)p;
      }
    ls += __shfl_xor(ls, 16);
    ls += __shfl_xor(ls, 32);
    lrun = lrun * fac + ls;
    mrun = mn;
    #pragma unroll
    for (int nd = 0; nd < 4; ++nd)
      #pragma unroll
      for (int r = 0; r < 4; ++r) oacc[nd][r] *= fac;

    // ---- P -> wave-private LDS, read back as B-frags ----
    #pragma unroll
    for (int nd = 0; nd < 4; ++nd)
      *(bf16x4*)(pw + swz16(qrow, 32 * nd + 8 * kgrp)) = pb[nd];
    bf16x8 ap[2];
    #pragma unroll
    for (int ks = 0; ks < 2; ++ks)
      ap[ks] = *(const bf16x8*)(pw + swz16(qrow, 64 * ks + 16 * kgrp));

    // ---- O^T += V^T P ----
    __builtin_amdgcn_s_setprio(1);
    #pragma unroll
    for (int ks = 0; ks < 2; ++ks)
      #pragma unroll
      for (int nd = 0; nd < 4; ++nd)
        oacc[nd] = __builtin_amdgcn_mfma_f32_16x16x32_bf16(vf[nd * 2 + ks], ap[ks], oacc[nd], 0, 0, 0);
    __builtin_amdgcn_s_setprio(0);
  }

  // ---- epilogue (lane-local, coalesced 16B stores) ----
  {
    const float inv = (lrun > 0.f) ? (1.f / lrun) : 0.f;
    const int grow = qb + 16 * rw + qrow;
    float* op = outg + ((size_t)(h * SEQ) + grow) * DH + 4 * kgrp;
    #pragma unroll
    for (int nd = 0; nd < 4; ++nd) {
      f32x4 o;
      #pragma unroll
      for (int r = 0; r < 4; ++r) o[r] = oacc[nd][r] * inv;
      *(f32x4*)(op + 16 * nd) = o;
    }
  }
}

extern "C" void kernel_launch(void* const* d_in, const int* in_sizes, int n_in,
                              void* d_out, int out_size, void* d_ws, size_t ws_size,
                              hipStream_t stream) {
  const float* q = (const float*)d_in[0];
  const float* k = (const float*)d_in[1];
  const float* v = (const float*)d_in[2];
  const void*  m = d_in[3];
  float* out = (float*)d_out;
  unsigned char* ws = (unsigned char*)d_ws;

  if (ws_size >= WS_NEED) {
    prep_kernel<true><<<512 + NH * NT * 4, 256, 0, stream>>>(k, v, m, ws);
    attn_kernel<true><<<NH * NT, 256, 0, stream>>>(q, k, v, m, out, ws);
  } else {
    prep_kernel<false><<<NH * NT * 4, 256, 0, stream>>>(k, v, m, ws);
    attn_kernel<false><<<NH * NT, 256, 0, stream>>>(q, k, v, m, out, ws);
  }
}